// Round 1
// baseline (1492.091 us; speedup 1.0000x reference)
//
#include <hip/hip_runtime.h>
#include <math.h>

#define DD 256
#define NHEADS 8
#define HDIM 32
#define NLAYERS 2
#define GSZ 64
#define KGRID 4096      // GS*GS
#define TTASK 4
#define BB 4
#define NMEAS 511
#define SSRC 512        // N+1
#define HCITY 128
#define WCITY 128
#define ATT_SCALE 0.17677669529663687f   // 32^-0.5
#define INV2S2 78.125f                   // 1/(2*0.08^2)

__device__ __forceinline__ float gelu_f(float x) {
    return 0.5f * x * (1.0f + erff(x * 0.7071067811865476f));
}

// ---------------------------------------------------------------------------
// task_vec[b][d] = task_emb[task_id[b]] @ taskp_W + taskp_b
__global__ void task_vec_kernel(const float* __restrict__ task_emb,
                                const float* __restrict__ tpW,
                                const float* __restrict__ tpb,
                                const int* __restrict__ task_id,
                                float* __restrict__ tv) {
    int b = blockIdx.x, t = threadIdx.x;
    int id = task_id[b];
    float a = tpb[t];
    for (int e = 0; e < DD; e++) a = fmaf(task_emb[id * DD + e], tpW[e * DD + t], a);
    tv[b * DD + t] = a;
}

// grid[b,k,d] = grid_pos[k,d] + task_vec[b,d]   (float4 elementwise)
__global__ void grid_init_kernel(const float* __restrict__ grid_pos,
                                 const float* __restrict__ tv,
                                 float* __restrict__ g) {
    int f = blockIdx.x * 256 + threadIdx.x;   // float4 index, total B*K*D/4 = 1048576
    int b = f >> 18;
    float4 gp = ((const float4*)grid_pos)[f & 262143];
    float4 tvv = ((const float4*)tv)[b * 64 + (f & 63)];
    float4 o; o.x = gp.x + tvv.x; o.y = gp.y + tvv.y; o.z = gp.z + tvv.z; o.w = gp.w + tvv.w;
    ((float4*)g)[f] = o;
}

// ---------------------------------------------------------------------------
// Build src tokens (meas + patch MLP, bs token) and src_xy.
__global__ __launch_bounds__(256) void src_build_kernel(
    const float* __restrict__ meas_xy, const float* __restrict__ meas_v,
    const float* __restrict__ bs_xy, const float* __restrict__ city,
    const float* __restrict__ meas_W, const float* __restrict__ meas_b,
    const float* __restrict__ pW1, const float* __restrict__ pb1,
    const float* __restrict__ pW2, const float* __restrict__ pb2,
    const float* __restrict__ bs_W, const float* __restrict__ bs_b,
    float* __restrict__ src, float* __restrict__ src_xy) {
    __shared__ float sp[81];
    __shared__ float sh[DD];
    int b = blockIdx.x / SSRC, s = blockIdx.x % SSRC, t = threadIdx.x;
    if (s < NMEAS) {
        float mx = meas_xy[(b * NMEAS + s) * 2];
        float my = meas_xy[(b * NMEAS + s) * 2 + 1];
        float mv = meas_v[b * NMEAS + s];
        int cx = (int)rintf(mx * 127.0f); cx = min(max(cx, 0), 127);
        int cy = (int)rintf(my * 127.0f); cy = min(max(cy, 0), 127);
        if (t < 81) {
            int rr = cy + t / 9 - 4, cc = cx + t % 9 - 4;
            sp[t] = (rr >= 0 && rr < HCITY && cc >= 0 && cc < WCITY)
                        ? city[(b * HCITY + rr) * WCITY + cc] : 0.0f;
        }
        __syncthreads();
        float a1 = pb1[t];
        #pragma unroll 9
        for (int e = 0; e < 81; e++) a1 = fmaf(sp[e], pW1[e * DD + t], a1);
        sh[t] = gelu_f(a1);
        __syncthreads();
        float a2 = pb2[t];
        for (int e = 0; e < DD; e++) a2 = fmaf(sh[e], pW2[e * DD + t], a2);
        float mt = mx * meas_W[t] + my * meas_W[DD + t] + mv * meas_W[2 * DD + t] + meas_b[t];
        src[((size_t)(b * SSRC + s)) * DD + t] = mt + a2;
        if (t == 0) { src_xy[(b * SSRC + s) * 2] = mx; src_xy[(b * SSRC + s) * 2 + 1] = my; }
    } else {
        float bx = bs_xy[b * 2], by = bs_xy[b * 2 + 1];
        src[((size_t)(b * SSRC + s)) * DD + t] = bx * bs_W[t] + by * bs_W[DD + t] + bs_b[t];
        if (t == 0) { src_xy[(b * SSRC + s) * 2] = bx; src_xy[(b * SSRC + s) * 2 + 1] = by; }
    }
}

// ---------------------------------------------------------------------------
// density[b,k] = mean_n exp(-|gxy_k - meas_xy_n|^2 / (2 sigma^2))
__global__ void density_kernel(const float* __restrict__ meas_xy, float* __restrict__ dens) {
    int w = threadIdx.x >> 6, lane = threadIdx.x & 63;
    int idx = blockIdx.x * 4 + w;        // b*K + k
    int b = idx >> 12, k = idx & 4095;
    float gx = ((k & 63) + 0.5f) * (1.0f / 64.0f);
    float gy = ((k >> 6) + 0.5f) * (1.0f / 64.0f);
    float s = 0.0f;
    for (int n = lane; n < NMEAS; n += 64) {
        float2 xy = ((const float2*)meas_xy)[b * NMEAS + n];
        float dx = gx - xy.x, dy = gy - xy.y;
        s += __expf(-(dx * dx + dy * dy) * INV2S2);
    }
    #pragma unroll
    for (int o = 1; o < 64; o <<= 1) s += __shfl_xor(s, o, 64);
    if (lane == 0) dens[idx] = s * (1.0f / 511.0f);
}

// ---------------------------------------------------------------------------
// LayerNorm: one wave per row of 256.
__global__ void ln_kernel(const float* __restrict__ X, const float* __restrict__ g,
                          const float* __restrict__ bvec, float* __restrict__ Y, int rows) {
    int w = threadIdx.x >> 6, lane = threadIdx.x & 63;
    int row = blockIdx.x * 4 + w;
    if (row >= rows) return;
    float4 x = ((const float4*)X)[(size_t)row * 64 + lane];
    float s = x.x + x.y + x.z + x.w;
    float q = x.x * x.x + x.y * x.y + x.z * x.z + x.w * x.w;
    #pragma unroll
    for (int o = 1; o < 64; o <<= 1) { s += __shfl_xor(s, o, 64); q += __shfl_xor(q, o, 64); }
    float m = s * (1.0f / 256.0f);
    float v = q * (1.0f / 256.0f) - m * m;
    float rs = rsqrtf(v + 1e-5f);
    float4 gg = ((const float4*)g)[lane], bb = ((const float4*)bvec)[lane];
    float4 y;
    y.x = (x.x - m) * rs * gg.x + bb.x;
    y.y = (x.y - m) * rs * gg.y + bb.y;
    y.z = (x.z - m) * rs * gg.z + bb.z;
    y.w = (x.w - m) * rs * gg.w + bb.w;
    ((float4*)Y)[(size_t)row * 64 + lane] = y;
}

// ---------------------------------------------------------------------------
// fp32 GEMM: C = [res +] act(A @ W + bias). Tile 64x128, BK=16, 256 thr, 4x8/thread.
template <int ACT, int RES, int BATW>
__global__ __launch_bounds__(256) void gemm_kernel(
    const float* __restrict__ A, const float* __restrict__ Wb,
    const float* __restrict__ bias, float* __restrict__ C,
    int M, int Kd, int Nd, const int* __restrict__ task_id, int wstride, int bstride) {
    __shared__ float sA[16][64];
    __shared__ float sB[16][128];
    int t = threadIdx.x;
    int m0 = blockIdx.x * 64, n0 = blockIdx.y * 128;
    const float* Wp = Wb;
    const float* bp = bias;
    if (BATW) {
        int b = m0 / KGRID;
        int id = task_id[b];
        Wp += (size_t)id * wstride;
        bp += (size_t)id * bstride;
    }
    int tm = t & 15, tn = t >> 4;
    float acc[4][8];
    #pragma unroll
    for (int i = 0; i < 4; i++)
        #pragma unroll
        for (int j = 0; j < 8; j++) acc[i][j] = 0.0f;
    int arow = t >> 2, akc = (t & 3) << 2;
    int bkr = t >> 4, bnc = (t & 15) << 2;
    for (int k0 = 0; k0 < Kd; k0 += 16) {
        float4 av = *(const float4*)(A + (size_t)(m0 + arow) * Kd + k0 + akc);
        float4 bv0 = *(const float4*)(Wp + (size_t)(k0 + bkr) * Nd + n0 + bnc);
        float4 bv1 = *(const float4*)(Wp + (size_t)(k0 + bkr) * Nd + n0 + bnc + 64);
        __syncthreads();
        sA[akc + 0][arow] = av.x;
        sA[akc + 1][arow] = av.y;
        sA[akc + 2][arow] = av.z;
        sA[akc + 3][arow] = av.w;
        *(float4*)&sB[bkr][bnc] = bv0;
        *(float4*)&sB[bkr][bnc + 64] = bv1;
        __syncthreads();
        #pragma unroll
        for (int kk = 0; kk < 16; kk++) {
            float4 a = *(const float4*)&sA[kk][tm << 2];
            float4 b0 = *(const float4*)&sB[kk][tn << 2];
            float4 b1 = *(const float4*)&sB[kk][(tn << 2) + 64];
            float aa[4] = {a.x, a.y, a.z, a.w};
            float bbv[8] = {b0.x, b0.y, b0.z, b0.w, b1.x, b1.y, b1.z, b1.w};
            #pragma unroll
            for (int i = 0; i < 4; i++)
                #pragma unroll
                for (int j = 0; j < 8; j++) acc[i][j] = fmaf(aa[i], bbv[j], acc[i][j]);
        }
    }
    float4 bs0 = *(const float4*)(bp + n0 + (tn << 2));
    float4 bs1 = *(const float4*)(bp + n0 + (tn << 2) + 64);
    #pragma unroll
    for (int i = 0; i < 4; i++) {
        int r = m0 + (tm << 2) + i;
        float o[8];
        o[0] = acc[i][0] + bs0.x; o[1] = acc[i][1] + bs0.y;
        o[2] = acc[i][2] + bs0.z; o[3] = acc[i][3] + bs0.w;
        o[4] = acc[i][4] + bs1.x; o[5] = acc[i][5] + bs1.y;
        o[6] = acc[i][6] + bs1.z; o[7] = acc[i][7] + bs1.w;
        if (ACT) {
            #pragma unroll
            for (int j = 0; j < 8; j++) o[j] = gelu_f(o[j]);
        }
        float* cp = C + (size_t)r * Nd + n0 + (tn << 2);
        if (RES) {
            float4 r0 = *(const float4*)cp;
            float4 r1 = *(const float4*)(cp + 64);
            o[0] += r0.x; o[1] += r0.y; o[2] += r0.z; o[3] += r0.w;
            o[4] += r1.x; o[5] += r1.y; o[6] += r1.z; o[7] += r1.w;
        }
        float4 w0 = {o[0], o[1], o[2], o[3]}, w1 = {o[4], o[5], o[6], o[7]};
        *(float4*)cp = w0;
        *(float4*)(cp + 64) = w1;
    }
}

// ---------------------------------------------------------------------------
// Fused attention: block = 256 rows of one (b,h); d split 4-way across lanes.
// scores = gate*(SCALE*q.k - softplus(dist)*|gxy-sxy|); softmax over S=512; out = attn@V.
#define APAD 36
__global__ __launch_bounds__(256) void attn_kernel(
    const float* __restrict__ Q, const float* __restrict__ Kb, const float* __restrict__ Vb,
    const float* __restrict__ sxy_g, const float* __restrict__ dens,
    const float* __restrict__ dist_raw, const float* __restrict__ dens_raw,
    float* __restrict__ O) {
    __shared__ float sK[128 * APAD];
    __shared__ float sV[128 * APAD];
    __shared__ float sxy[128 * 2];
    int blk = blockIdx.x;
    int kt = blk & 15, h = (blk >> 4) & 7, b = blk >> 7;
    int t = threadIdx.x, sg = t & 3, qg = t >> 2;
    float c1 = log1pf(__expf(dist_raw[0]));
    float th = tanhf(dens_raw[0]);
    float qv[4][8], ov[4][8], l[4], gate[4], gx[4], gy[4];
    #pragma unroll
    for (int r = 0; r < 4; r++) {
        int row = kt * 256 + qg * 4 + r;
        gx[r] = ((row & 63) + 0.5f) * (1.0f / 64.0f);
        gy[r] = ((row >> 6) + 0.5f) * (1.0f / 64.0f);
        gate[r] = 1.0f + th * dens[b * KGRID + row];
        const float* qp = Q + ((size_t)(b * KGRID + row)) * DD + h * HDIM + sg * 8;
        float4 q0 = *(const float4*)qp, q1 = *(const float4*)(qp + 4);
        qv[r][0] = q0.x; qv[r][1] = q0.y; qv[r][2] = q0.z; qv[r][3] = q0.w;
        qv[r][4] = q1.x; qv[r][5] = q1.y; qv[r][6] = q1.z; qv[r][7] = q1.w;
        l[r] = 0.0f;
        #pragma unroll
        for (int j = 0; j < 8; j++) ov[r][j] = 0.0f;
    }
    int srow = t >> 1, sc0 = (t & 1) * 16;
    for (int st = 0; st < SSRC; st += 128) {
        const float* kp = Kb + ((size_t)(b * SSRC + st + srow)) * DD + h * HDIM + sc0;
        const float* vp = Vb + ((size_t)(b * SSRC + st + srow)) * DD + h * HDIM + sc0;
        float4 kf[4], vf[4];
        #pragma unroll
        for (int i = 0; i < 4; i++) { kf[i] = *(const float4*)(kp + 4 * i); vf[i] = *(const float4*)(vp + 4 * i); }
        float2 xyld = {0.f, 0.f};
        if (t < 128) xyld = *(const float2*)(sxy_g + (size_t)(b * SSRC + st + t) * 2);
        __syncthreads();
        #pragma unroll
        for (int i = 0; i < 4; i++) {
            *(float4*)&sK[srow * APAD + sc0 + 4 * i] = kf[i];
            *(float4*)&sV[srow * APAD + sc0 + 4 * i] = vf[i];
        }
        if (t < 128) { sxy[t * 2] = xyld.x; sxy[t * 2 + 1] = xyld.y; }
        __syncthreads();
        for (int s = 0; s < 128; s++) {
            float4 k0 = *(const float4*)&sK[s * APAD + sg * 8];
            float4 k1 = *(const float4*)&sK[s * APAD + sg * 8 + 4];
            float kr[8] = {k0.x, k0.y, k0.z, k0.w, k1.x, k1.y, k1.z, k1.w};
            float4 v0 = *(const float4*)&sV[s * APAD + sg * 8];
            float4 v1 = *(const float4*)&sV[s * APAD + sg * 8 + 4];
            float vr[8] = {v0.x, v0.y, v0.z, v0.w, v1.x, v1.y, v1.z, v1.w};
            float sx = sxy[s * 2], sy = sxy[s * 2 + 1];
            #pragma unroll
            for (int r = 0; r < 4; r++) {
                float d = 0.0f;
                #pragma unroll
                for (int j = 0; j < 8; j++) d = fmaf(qv[r][j], kr[j], d);
                d += __shfl_xor(d, 1, 64);
                d += __shfl_xor(d, 2, 64);
                float dx = gx[r] - sx, dy = gy[r] - sy;
                float sc = gate[r] * (ATT_SCALE * d - c1 * sqrtf(dx * dx + dy * dy));
                float p = __expf(sc);
                l[r] += p;
                #pragma unroll
                for (int j = 0; j < 8; j++) ov[r][j] = fmaf(p, vr[j], ov[r][j]);
            }
        }
        __syncthreads();
    }
    #pragma unroll
    for (int r = 0; r < 4; r++) {
        float inv = 1.0f / l[r];
        int row = kt * 256 + qg * 4 + r;
        float* op = O + ((size_t)(b * KGRID + row)) * DD + h * HDIM + sg * 8;
        float4 w0 = {ov[r][0] * inv, ov[r][1] * inv, ov[r][2] * inv, ov[r][3] * inv};
        float4 w1 = {ov[r][4] * inv, ov[r][5] * inv, ov[r][6] * inv, ov[r][7] * inv};
        *(float4*)op = w0;
        *(float4*)(op + 4) = w1;
    }
}

// ---------------------------------------------------------------------------
// logits[b,k] = tf[b,k,:] . head_W + head_b   (wave per row)
__global__ void head_kernel(const float* __restrict__ tf, const float* __restrict__ hW,
                            const float* __restrict__ hb, float* __restrict__ out) {
    int w = threadIdx.x >> 6, lane = threadIdx.x & 63;
    int idx = blockIdx.x * 4 + w;
    float4 x = ((const float4*)tf)[(size_t)idx * 64 + lane];
    float4 ww = ((const float4*)hW)[lane];
    float s = x.x * ww.x + x.y * ww.y + x.z * ww.z + x.w * ww.w;
    #pragma unroll
    for (int o = 1; o < 64; o <<= 1) s += __shfl_xor(s, o, 64);
    if (lane == 0) out[idx] = s + hb[0];
}

// ---------------------------------------------------------------------------
extern "C" void kernel_launch(void* const* d_in, const int* in_sizes, int n_in,
                              void* d_out, int out_size, void* d_ws, size_t ws_size,
                              hipStream_t stream) {
    const float* meas_xy = (const float*)d_in[0];
    const float* meas_v  = (const float*)d_in[1];
    const float* bs_xy   = (const float*)d_in[2];
    const float* city    = (const float*)d_in[3];
    const float* meas_W  = (const float*)d_in[4];
    const float* meas_b  = (const float*)d_in[5];
    const float* pW1     = (const float*)d_in[6];
    const float* pb1     = (const float*)d_in[7];
    const float* pW2     = (const float*)d_in[8];
    const float* pb2     = (const float*)d_in[9];
    const float* bs_W    = (const float*)d_in[10];
    const float* bs_b    = (const float*)d_in[11];
    const float* task_emb= (const float*)d_in[12];
    const float* taskp_W = (const float*)d_in[13];
    const float* taskp_b = (const float*)d_in[14];
    const float* grid_pos= (const float*)d_in[15];
    const float* lnq_g   = (const float*)d_in[16];
    const float* lnq_b   = (const float*)d_in[17];
    const float* lnkv_g  = (const float*)d_in[18];
    const float* lnkv_b  = (const float*)d_in[19];
    const float* qW      = (const float*)d_in[20];
    const float* qb      = (const float*)d_in[21];
    const float* kW      = (const float*)d_in[22];
    const float* kb      = (const float*)d_in[23];
    const float* vW      = (const float*)d_in[24];
    const float* vb      = (const float*)d_in[25];
    const float* oW      = (const float*)d_in[26];
    const float* ob      = (const float*)d_in[27];
    const float* dist_raw= (const float*)d_in[28];
    const float* dens_raw= (const float*)d_in[29];
    const float* lnf_g   = (const float*)d_in[30];
    const float* lnf_b   = (const float*)d_in[31];
    const float* f1W     = (const float*)d_in[32];
    const float* f1b     = (const float*)d_in[33];
    const float* f2W     = (const float*)d_in[34];
    const float* f2b     = (const float*)d_in[35];
    const float* tfp_W   = (const float*)d_in[36];
    const float* tfp_b   = (const float*)d_in[37];
    const float* head_W  = (const float*)d_in[38];
    const float* head_b  = (const float*)d_in[39];
    const int*   task_id = (const int*)d_in[40];

    float* ws = (float*)d_ws;
    const size_t SRC_N = (size_t)BB * SSRC * DD;      // 524288
    const size_t GRD_N = (size_t)BB * KGRID * DD;     // 4194304
    float* src   = ws;
    float* kv_in = src + SRC_N;
    float* kbuf  = kv_in + SRC_N;
    float* vbuf  = kbuf + SRC_N;
    float* gridb = vbuf + SRC_N;
    float* tmp1  = gridb + GRD_N;
    float* tmp2  = tmp1 + GRD_N;
    float* tmp3  = tmp2 + GRD_N;                      // B*K*2D
    float* sxy   = tmp3 + 2 * GRD_N;
    float* dens  = sxy + (size_t)BB * SSRC * 2;
    float* tvec  = dens + (size_t)BB * KGRID;

    const int MR = BB * KGRID;   // 16384
    const int MS = BB * SSRC;    // 2048

    task_vec_kernel<<<BB, 256, 0, stream>>>(task_emb, taskp_W, taskp_b, task_id, tvec);
    grid_init_kernel<<<4096, 256, 0, stream>>>(grid_pos, tvec, gridb);
    src_build_kernel<<<BB * SSRC, 256, 0, stream>>>(meas_xy, meas_v, bs_xy, city,
                                                    meas_W, meas_b, pW1, pb1, pW2, pb2,
                                                    bs_W, bs_b, src, sxy);
    density_kernel<<<(BB * KGRID) / 4, 256, 0, stream>>>(meas_xy, dens);

    for (int i = 0; i < NLAYERS; i++) {
        const int wso = i * DD * DD, bso = i * DD;
        ln_kernel<<<MS / 4, 256, 0, stream>>>(src, lnkv_g + bso, lnkv_b + bso, kv_in, MS);
        gemm_kernel<0, 0, 0><<<dim3(MS / 64, 2), 256, 0, stream>>>(
            kv_in, kW + wso, kb + bso, kbuf, MS, DD, DD, nullptr, 0, 0);
        gemm_kernel<0, 0, 0><<<dim3(MS / 64, 2), 256, 0, stream>>>(
            kv_in, vW + wso, vb + bso, vbuf, MS, DD, DD, nullptr, 0, 0);
        ln_kernel<<<MR / 4, 256, 0, stream>>>(gridb, lnq_g + bso, lnq_b + bso, tmp1, MR);
        gemm_kernel<0, 0, 0><<<dim3(MR / 64, 2), 256, 0, stream>>>(
            tmp1, qW + wso, qb + bso, tmp2, MR, DD, DD, nullptr, 0, 0);
        attn_kernel<<<BB * NHEADS * (KGRID / 256), 256, 0, stream>>>(
            tmp2, kbuf, vbuf, sxy, dens, dist_raw + i, dens_raw + i, tmp1);
        gemm_kernel<0, 1, 0><<<dim3(MR / 64, 2), 256, 0, stream>>>(
            tmp1, oW + wso, ob + bso, gridb, MR, DD, DD, nullptr, 0, 0);
        ln_kernel<<<MR / 4, 256, 0, stream>>>(gridb, lnf_g + bso, lnf_b + bso, tmp1, MR);
        gemm_kernel<1, 0, 0><<<dim3(MR / 64, 4), 256, 0, stream>>>(
            tmp1, f1W + i * DD * 2 * DD, f1b + i * 2 * DD, tmp3, MR, DD, 2 * DD, nullptr, 0, 0);
        gemm_kernel<0, 1, 0><<<dim3(MR / 64, 2), 256, 0, stream>>>(
            tmp3, f2W + i * 2 * DD * DD, f2b + bso, gridb, MR, 2 * DD, DD, nullptr, 0, 0);
    }

    gemm_kernel<1, 0, 1><<<dim3(MR / 64, 2), 256, 0, stream>>>(
        gridb, tfp_W, tfp_b, tmp1, MR, DD, DD, task_id, DD * DD, DD);
    head_kernel<<<MR / 4, 256, 0, stream>>>(tmp1, head_W, head_b, (float*)d_out);
}

// Round 3
// 913.515 us; speedup vs baseline: 1.6334x; 1.6334x over previous
//
#include <hip/hip_runtime.h>
#include <math.h>

#define DD 256
#define NHEADS 8
#define HDIM 32
#define NLAYERS 2
#define GSZ 64
#define KGRID 4096      // GS*GS
#define TTASK 4
#define BB 4
#define NMEAS 511
#define SSRC 512        // N+1
#define HCITY 128
#define WCITY 128
#define ATT_SCALE 0.17677669529663687f   // 32^-0.5
#define INV2S2 78.125f                   // 1/(2*0.08^2)

typedef __attribute__((ext_vector_type(8))) short short8;
typedef __attribute__((ext_vector_type(4))) float f32x4;

union PK8 { unsigned int u[4]; short8 v; };

__device__ __forceinline__ unsigned short f2bf(float f) {
    union { float f; unsigned int u; } x; x.f = f;
    return (unsigned short)((x.u + 0x7fffu + ((x.u >> 16) & 1u)) >> 16);
}

__device__ __forceinline__ float gelu_f(float x) {
    return 0.5f * x * (1.0f + erff(x * 0.7071067811865476f));
}

// ---------------------------------------------------------------------------
// task_vec[b][d] = task_emb[task_id[b]] @ taskp_W + taskp_b
__global__ void task_vec_kernel(const float* __restrict__ task_emb,
                                const float* __restrict__ tpW,
                                const float* __restrict__ tpb,
                                const int* __restrict__ task_id,
                                float* __restrict__ tv) {
    int b = blockIdx.x, t = threadIdx.x;
    int id = task_id[b];
    float a = tpb[t];
    for (int e = 0; e < DD; e++) a = fmaf(task_emb[id * DD + e], tpW[e * DD + t], a);
    tv[b * DD + t] = a;
}

// grid[b,k,d] = grid_pos[k,d] + task_vec[b,d]   (float4 elementwise)
__global__ void grid_init_kernel(const float* __restrict__ grid_pos,
                                 const float* __restrict__ tv,
                                 float* __restrict__ g) {
    int f = blockIdx.x * 256 + threadIdx.x;   // float4 index, total B*K*D/4 = 1048576
    int b = f >> 18;
    float4 gp = ((const float4*)grid_pos)[f & 262143];
    float4 tvv = ((const float4*)tv)[b * 64 + (f & 63)];
    float4 o; o.x = gp.x + tvv.x; o.y = gp.y + tvv.y; o.z = gp.z + tvv.z; o.w = gp.w + tvv.w;
    ((float4*)g)[f] = o;
}

// ---------------------------------------------------------------------------
// Build src tokens (meas + patch MLP, bs token) and src_xy.
__global__ __launch_bounds__(256) void src_build_kernel(
    const float* __restrict__ meas_xy, const float* __restrict__ meas_v,
    const float* __restrict__ bs_xy, const float* __restrict__ city,
    const float* __restrict__ meas_W, const float* __restrict__ meas_b,
    const float* __restrict__ pW1, const float* __restrict__ pb1,
    const float* __restrict__ pW2, const float* __restrict__ pb2,
    const float* __restrict__ bs_W, const float* __restrict__ bs_b,
    float* __restrict__ src, float* __restrict__ src_xy) {
    __shared__ float sp[81];
    __shared__ float sh[DD];
    int b = blockIdx.x / SSRC, s = blockIdx.x % SSRC, t = threadIdx.x;
    if (s < NMEAS) {
        float mx = meas_xy[(b * NMEAS + s) * 2];
        float my = meas_xy[(b * NMEAS + s) * 2 + 1];
        float mv = meas_v[b * NMEAS + s];
        int cx = (int)rintf(mx * 127.0f); cx = min(max(cx, 0), 127);
        int cy = (int)rintf(my * 127.0f); cy = min(max(cy, 0), 127);
        if (t < 81) {
            int rr = cy + t / 9 - 4, cc = cx + t % 9 - 4;
            sp[t] = (rr >= 0 && rr < HCITY && cc >= 0 && cc < WCITY)
                        ? city[(b * HCITY + rr) * WCITY + cc] : 0.0f;
        }
        __syncthreads();
        float a1 = pb1[t];
        #pragma unroll 9
        for (int e = 0; e < 81; e++) a1 = fmaf(sp[e], pW1[e * DD + t], a1);
        sh[t] = gelu_f(a1);
        __syncthreads();
        float a2 = pb2[t];
        for (int e = 0; e < DD; e++) a2 = fmaf(sh[e], pW2[e * DD + t], a2);
        float mt = mx * meas_W[t] + my * meas_W[DD + t] + mv * meas_W[2 * DD + t] + meas_b[t];
        src[((size_t)(b * SSRC + s)) * DD + t] = mt + a2;
        if (t == 0) { src_xy[(b * SSRC + s) * 2] = mx; src_xy[(b * SSRC + s) * 2 + 1] = my; }
    } else {
        float bx = bs_xy[b * 2], by = bs_xy[b * 2 + 1];
        src[((size_t)(b * SSRC + s)) * DD + t] = bx * bs_W[t] + by * bs_W[DD + t] + bs_b[t];
        if (t == 0) { src_xy[(b * SSRC + s) * 2] = bx; src_xy[(b * SSRC + s) * 2 + 1] = by; }
    }
}

// ---------------------------------------------------------------------------
// density[b,k] = mean_n exp(-|gxy_k - meas_xy_n|^2 / (2 sigma^2))
__global__ void density_kernel(const float* __restrict__ meas_xy, float* __restrict__ dens) {
    int w = threadIdx.x >> 6, lane = threadIdx.x & 63;
    int idx = blockIdx.x * 4 + w;        // b*K + k
    int b = idx >> 12, k = idx & 4095;
    float gx = ((k & 63) + 0.5f) * (1.0f / 64.0f);
    float gy = ((k >> 6) + 0.5f) * (1.0f / 64.0f);
    float s = 0.0f;
    for (int n = lane; n < NMEAS; n += 64) {
        float2 xy = ((const float2*)meas_xy)[b * NMEAS + n];
        float dx = gx - xy.x, dy = gy - xy.y;
        s += __expf(-(dx * dx + dy * dy) * INV2S2);
    }
    #pragma unroll
    for (int o = 1; o < 64; o <<= 1) s += __shfl_xor(s, o, 64);
    if (lane == 0) dens[idx] = s * (1.0f / 511.0f);
}

// ---------------------------------------------------------------------------
// LayerNorm: one wave per row of 256.
__global__ void ln_kernel(const float* __restrict__ X, const float* __restrict__ g,
                          const float* __restrict__ bvec, float* __restrict__ Y, int rows) {
    int w = threadIdx.x >> 6, lane = threadIdx.x & 63;
    int row = blockIdx.x * 4 + w;
    if (row >= rows) return;
    float4 x = ((const float4*)X)[(size_t)row * 64 + lane];
    float s = x.x + x.y + x.z + x.w;
    float q = x.x * x.x + x.y * x.y + x.z * x.z + x.w * x.w;
    #pragma unroll
    for (int o = 1; o < 64; o <<= 1) { s += __shfl_xor(s, o, 64); q += __shfl_xor(q, o, 64); }
    float m = s * (1.0f / 256.0f);
    float v = q * (1.0f / 256.0f) - m * m;
    float rs = rsqrtf(v + 1e-5f);
    float4 gg = ((const float4*)g)[lane], bb = ((const float4*)bvec)[lane];
    float4 y;
    y.x = (x.x - m) * rs * gg.x + bb.x;
    y.y = (x.y - m) * rs * gg.y + bb.y;
    y.z = (x.z - m) * rs * gg.z + bb.z;
    y.w = (x.w - m) * rs * gg.w + bb.w;
    ((float4*)Y)[(size_t)row * 64 + lane] = y;
}

// ---------------------------------------------------------------------------
// fp32 GEMM: C = [res +] act(A @ W + bias). Tile 64x128, BK=16, 256 thr, 4x8/thread.
template <int ACT, int RES, int BATW>
__global__ __launch_bounds__(256) void gemm_kernel(
    const float* __restrict__ A, const float* __restrict__ Wb,
    const float* __restrict__ bias, float* __restrict__ C,
    int M, int Kd, int Nd, const int* __restrict__ task_id, int wstride, int bstride) {
    __shared__ float sA[16][64];
    __shared__ float sB[16][128];
    int t = threadIdx.x;
    int m0 = blockIdx.x * 64, n0 = blockIdx.y * 128;
    const float* Wp = Wb;
    const float* bp = bias;
    if (BATW) {
        int b = m0 / KGRID;
        int id = task_id[b];
        Wp += (size_t)id * wstride;
        bp += (size_t)id * bstride;
    }
    int tm = t & 15, tn = t >> 4;
    float acc[4][8];
    #pragma unroll
    for (int i = 0; i < 4; i++)
        #pragma unroll
        for (int j = 0; j < 8; j++) acc[i][j] = 0.0f;
    int arow = t >> 2, akc = (t & 3) << 2;
    int bkr = t >> 4, bnc = (t & 15) << 2;
    for (int k0 = 0; k0 < Kd; k0 += 16) {
        float4 av = *(const float4*)(A + (size_t)(m0 + arow) * Kd + k0 + akc);
        float4 bv0 = *(const float4*)(Wp + (size_t)(k0 + bkr) * Nd + n0 + bnc);
        float4 bv1 = *(const float4*)(Wp + (size_t)(k0 + bkr) * Nd + n0 + bnc + 64);
        __syncthreads();
        sA[akc + 0][arow] = av.x;
        sA[akc + 1][arow] = av.y;
        sA[akc + 2][arow] = av.z;
        sA[akc + 3][arow] = av.w;
        *(float4*)&sB[bkr][bnc] = bv0;
        *(float4*)&sB[bkr][bnc + 64] = bv1;
        __syncthreads();
        #pragma unroll
        for (int kk = 0; kk < 16; kk++) {
            float4 a = *(const float4*)&sA[kk][tm << 2];
            float4 b0 = *(const float4*)&sB[kk][tn << 2];
            float4 b1 = *(const float4*)&sB[kk][(tn << 2) + 64];
            float aa[4] = {a.x, a.y, a.z, a.w};
            float bbv[8] = {b0.x, b0.y, b0.z, b0.w, b1.x, b1.y, b1.z, b1.w};
            #pragma unroll
            for (int i = 0; i < 4; i++)
                #pragma unroll
                for (int j = 0; j < 8; j++) acc[i][j] = fmaf(aa[i], bbv[j], acc[i][j]);
        }
    }
    float4 bs0 = *(const float4*)(bp + n0 + (tn << 2));
    float4 bs1 = *(const float4*)(bp + n0 + (tn << 2) + 64);
    #pragma unroll
    for (int i = 0; i < 4; i++) {
        int r = m0 + (tm << 2) + i;
        float o[8];
        o[0] = acc[i][0] + bs0.x; o[1] = acc[i][1] + bs0.y;
        o[2] = acc[i][2] + bs0.z; o[3] = acc[i][3] + bs0.w;
        o[4] = acc[i][4] + bs1.x; o[5] = acc[i][5] + bs1.y;
        o[6] = acc[i][6] + bs1.z; o[7] = acc[i][7] + bs1.w;
        if (ACT) {
            #pragma unroll
            for (int j = 0; j < 8; j++) o[j] = gelu_f(o[j]);
        }
        float* cp = C + (size_t)r * Nd + n0 + (tn << 2);
        if (RES) {
            float4 r0 = *(const float4*)cp;
            float4 r1 = *(const float4*)(cp + 64);
            o[0] += r0.x; o[1] += r0.y; o[2] += r0.z; o[3] += r0.w;
            o[4] += r1.x; o[5] += r1.y; o[6] += r1.z; o[7] += r1.w;
        }
        float4 w0 = {o[0], o[1], o[2], o[3]}, w1 = {o[4], o[5], o[6], o[7]};
        *(float4*)cp = w0;
        *(float4*)(cp + 64) = w1;
    }
}

// ---------------------------------------------------------------------------
// MFMA attention (bf16 QK/PV, fp32 softmax), swapped-operand layout.
// Block = (b, h, 64 q-rows); 4 waves x 16 q-rows; full S=512 staged in LDS.
// Per 16-s tile: D = mfma(K_tile, Q_frag) -> D[s_local = 4g+r, q = lane&15].
// softmax lane-local (q fixed per lane); P written to per-wave LDS [q][s] bf16,
// read back as B-frag (conflict-free dense b128); PV: O^T = mfma(V^T, P^T).
#define VTS 520   // Vt row stride (bf16) = 512 + 8 pad -> spreads banks
__global__ __launch_bounds__(256) void attn_mfma_kernel(
    const float* __restrict__ Q, const float* __restrict__ Kb, const float* __restrict__ Vb,
    const float* __restrict__ sxy_g, const float* __restrict__ dens,
    const float* __restrict__ dist_raw, const float* __restrict__ dens_raw,
    float* __restrict__ O) {
    __shared__ unsigned short sK[SSRC * 32];        // [s][d] bf16, stride 64B
    __shared__ unsigned short sVt[32 * VTS];        // [d][s] bf16 transposed
    __shared__ float2 sxy[SSRC];
    __shared__ unsigned short sP[4][16 * 32];       // per-wave P [q][s] bf16

    int blk = blockIdx.x;
    int kt = blk & 63, h = (blk >> 6) & 7, b = blk >> 9;
    int t = threadIdx.x;

    // ---- stage K as bf16 [s][32] ----
    #pragma unroll
    for (int rr = 0; rr < 2; rr++) {
        int s = t + rr * 256;
        const float* kp = Kb + ((size_t)(b * SSRC + s)) * DD + h * HDIM;
        float4 f[8];
        #pragma unroll
        for (int i = 0; i < 8; i++) f[i] = ((const float4*)kp)[i];
        unsigned int pk[16];
        #pragma unroll
        for (int i = 0; i < 8; i++) {
            pk[2 * i]     = f2bf(f[i].x) | ((unsigned)f2bf(f[i].y) << 16);
            pk[2 * i + 1] = f2bf(f[i].z) | ((unsigned)f2bf(f[i].w) << 16);
        }
        uint4* dst = (uint4*)&sK[s * 32];
        #pragma unroll
        for (int j = 0; j < 4; j++)
            dst[j] = make_uint4(pk[4 * j], pk[4 * j + 1], pk[4 * j + 2], pk[4 * j + 3]);
    }
    // ---- stage V transposed: sVt[d][s] (pairs of s per b32 write) ----
    {
        int sv = 2 * t;
        const float* vp0 = Vb + ((size_t)(b * SSRC + sv)) * DD + h * HDIM;
        const float* vp1 = vp0 + DD;
        float4 a0[8], a1[8];
        #pragma unroll
        for (int i = 0; i < 8; i++) { a0[i] = ((const float4*)vp0)[i]; a1[i] = ((const float4*)vp1)[i]; }
        #pragma unroll
        for (int i = 0; i < 8; i++) {
            const float* e0 = (const float*)&a0[i];
            const float* e1 = (const float*)&a1[i];
            #pragma unroll
            for (int jj = 0; jj < 4; jj++) {
                int d = i * 4 + jj;
                *(unsigned int*)&sVt[d * VTS + sv] =
                    f2bf(e0[jj]) | ((unsigned)f2bf(e1[jj]) << 16);
            }
        }
    }
    sxy[t]       = ((const float2*)sxy_g)[b * SSRC + t];
    sxy[t + 256] = ((const float2*)sxy_g)[b * SSRC + t + 256];
    __syncthreads();

    int lane = t & 63, w = t >> 6;
    int lq = lane & 15, g = lane >> 4;
    int qrow = kt * 64 + w * 16 + lq;
    float gx = ((qrow & 63) + 0.5f) * (1.0f / 64.0f);
    float gy = ((qrow >> 6) + 0.5f) * (1.0f / 64.0f);
    const float LOG2E = 1.4426950408889634f;
    float gate = 1.0f + tanhf(dens_raw[0]) * dens[b * KGRID + qrow];
    float c1 = log1pf(__expf(dist_raw[0]));
    float gs = gate * ATT_SCALE * LOG2E;     // folded into exp2
    float gc = gate * c1 * LOG2E;

    PK8 qf;
    {
        const float* qp = Q + ((size_t)(b * KGRID + qrow)) * DD + h * HDIM + g * 8;
        float4 q0 = *(const float4*)qp, q1 = *(const float4*)(qp + 4);
        qf.u[0] = f2bf(q0.x) | ((unsigned)f2bf(q0.y) << 16);
        qf.u[1] = f2bf(q0.z) | ((unsigned)f2bf(q0.w) << 16);
        qf.u[2] = f2bf(q1.x) | ((unsigned)f2bf(q1.y) << 16);
        qf.u[3] = f2bf(q1.z) | ((unsigned)f2bf(q1.w) << 16);
    }
    f32x4 acc0 = {0.f, 0.f, 0.f, 0.f}, acc1 = {0.f, 0.f, 0.f, 0.f};
    f32x4 zero = {0.f, 0.f, 0.f, 0.f};
    float lsum = 0.0f;
    unsigned short* myP = &sP[w][0];

    for (int s0 = 0; s0 < SSRC; s0 += 32) {
        #pragma unroll
        for (int tl = 0; tl < 2; tl++) {
            int sb = s0 + tl * 16;
            short8 kf = *(const short8*)&sK[(sb + lq) * 32 + g * 8];
            f32x4 c = __builtin_amdgcn_mfma_f32_16x16x32_bf16(kf, qf.v, zero, 0, 0, 0);
            float p[4];
            #pragma unroll
            for (int r = 0; r < 4; r++) {
                int s = sb + 4 * g + r;
                float2 xy = sxy[s];
                float dx = gx - xy.x, dy = gy - xy.y;
                float dist = sqrtf(dx * dx + dy * dy);
                p[r] = exp2f(gs * c[r] - gc * dist);
                lsum += p[r];
            }
            int idx = lq * 32 + tl * 16 + 4 * g;
            *(unsigned int*)&myP[idx]     = f2bf(p[0]) | ((unsigned)f2bf(p[1]) << 16);
            *(unsigned int*)&myP[idx + 2] = f2bf(p[2]) | ((unsigned)f2bf(p[3]) << 16);
        }
        short8 pf = *(const short8*)&myP[lq * 32 + g * 8];
        short8 v0 = *(const short8*)&sVt[lq * VTS + s0 + g * 8];
        short8 v1 = *(const short8*)&sVt[(16 + lq) * VTS + s0 + g * 8];
        acc0 = __builtin_amdgcn_mfma_f32_16x16x32_bf16(v0, pf, acc0, 0, 0, 0);
        acc1 = __builtin_amdgcn_mfma_f32_16x16x32_bf16(v1, pf, acc1, 0, 0, 0);
    }

    lsum += __shfl_xor(lsum, 16, 64);
    lsum += __shfl_xor(lsum, 32, 64);
    float inv = 1.0f / lsum;
    float* op = O + ((size_t)(b * KGRID + qrow)) * DD + h * HDIM + 4 * g;
    float4 w0 = {acc0[0] * inv, acc0[1] * inv, acc0[2] * inv, acc0[3] * inv};
    float4 w1 = {acc1[0] * inv, acc1[1] * inv, acc1[2] * inv, acc1[3] * inv};
    *(float4*)op = w0;
    *(float4*)(op + 16) = w1;
}

// ---------------------------------------------------------------------------
// logits[b,k] = tf[b,k,:] . head_W + head_b   (wave per row)
__global__ void head_kernel(const float* __restrict__ tf, const float* __restrict__ hW,
                            const float* __restrict__ hb, float* __restrict__ out) {
    int w = threadIdx.x >> 6, lane = threadIdx.x & 63;
    int idx = blockIdx.x * 4 + w;
    float4 x = ((const float4*)tf)[(size_t)idx * 64 + lane];
    float4 ww = ((const float4*)hW)[lane];
    float s = x.x * ww.x + x.y * ww.y + x.z * ww.z + x.w * ww.w;
    #pragma unroll
    for (int o = 1; o < 64; o <<= 1) s += __shfl_xor(s, o, 64);
    if (lane == 0) out[idx] = s + hb[0];
}

// ---------------------------------------------------------------------------
extern "C" void kernel_launch(void* const* d_in, const int* in_sizes, int n_in,
                              void* d_out, int out_size, void* d_ws, size_t ws_size,
                              hipStream_t stream) {
    const float* meas_xy = (const float*)d_in[0];
    const float* meas_v  = (const float*)d_in[1];
    const float* bs_xy   = (const float*)d_in[2];
    const float* city    = (const float*)d_in[3];
    const float* meas_W  = (const float*)d_in[4];
    const float* meas_b  = (const float*)d_in[5];
    const float* pW1     = (const float*)d_in[6];
    const float* pb1     = (const float*)d_in[7];
    const float* pW2     = (const float*)d_in[8];
    const float* pb2     = (const float*)d_in[9];
    const float* bs_W    = (const float*)d_in[10];
    const float* bs_b    = (const float*)d_in[11];
    const float* task_emb= (const float*)d_in[12];
    const float* taskp_W = (const float*)d_in[13];
    const float* taskp_b = (const float*)d_in[14];
    const float* grid_pos= (const float*)d_in[15];
    const float* lnq_g   = (const float*)d_in[16];
    const float* lnq_b   = (const float*)d_in[17];
    const float* lnkv_g  = (const float*)d_in[18];
    const float* lnkv_b  = (const float*)d_in[19];
    const float* qW      = (const float*)d_in[20];
    const float* qb      = (const float*)d_in[21];
    const float* kW      = (const float*)d_in[22];
    const float* kb      = (const float*)d_in[23];
    const float* vW      = (const float*)d_in[24];
    const float* vb      = (const float*)d_in[25];
    const float* oW      = (const float*)d_in[26];
    const float* ob      = (const float*)d_in[27];
    const float* dist_raw= (const float*)d_in[28];
    const float* dens_raw= (const float*)d_in[29];
    const float* lnf_g   = (const float*)d_in[30];
    const float* lnf_b   = (const float*)d_in[31];
    const float* f1W     = (const float*)d_in[32];
    const float* f1b     = (const float*)d_in[33];
    const float* f2W     = (const float*)d_in[34];
    const float* f2b     = (const float*)d_in[35];
    const float* tfp_W   = (const float*)d_in[36];
    const float* tfp_b   = (const float*)d_in[37];
    const float* head_W  = (const float*)d_in[38];
    const float* head_b  = (const float*)d_in[39];
    const int*   task_id = (const int*)d_in[40];

    float* ws = (float*)d_ws;
    const size_t SRC_N = (size_t)BB * SSRC * DD;      // 524288
    const size_t GRD_N = (size_t)BB * KGRID * DD;     // 4194304
    float* src   = ws;
    float* kv_in = src + SRC_N;
    float* kbuf  = kv_in + SRC_N;
    float* vbuf  = kbuf + SRC_N;
    float* gridb = vbuf + SRC_N;
    float* tmp1  = gridb + GRD_N;
    float* tmp2  = tmp1 + GRD_N;
    float* tmp3  = tmp2 + GRD_N;                      // B*K*2D
    float* sxy   = tmp3 + 2 * GRD_N;
    float* dens  = sxy + (size_t)BB * SSRC * 2;
    float* tvec  = dens + (size_t)BB * KGRID;

    const int MR = BB * KGRID;   // 16384
    const int MS = BB * SSRC;    // 2048

    task_vec_kernel<<<BB, 256, 0, stream>>>(task_emb, taskp_W, taskp_b, task_id, tvec);
    grid_init_kernel<<<4096, 256, 0, stream>>>(grid_pos, tvec, gridb);
    src_build_kernel<<<BB * SSRC, 256, 0, stream>>>(meas_xy, meas_v, bs_xy, city,
                                                    meas_W, meas_b, pW1, pb1, pW2, pb2,
                                                    bs_W, bs_b, src, sxy);
    density_kernel<<<(BB * KGRID) / 4, 256, 0, stream>>>(meas_xy, dens);

    for (int i = 0; i < NLAYERS; i++) {
        const int wso = i * DD * DD, bso = i * DD;
        ln_kernel<<<MS / 4, 256, 0, stream>>>(src, lnkv_g + bso, lnkv_b + bso, kv_in, MS);
        gemm_kernel<0, 0, 0><<<dim3(MS / 64, 2), 256, 0, stream>>>(
            kv_in, kW + wso, kb + bso, kbuf, MS, DD, DD, nullptr, 0, 0);
        gemm_kernel<0, 0, 0><<<dim3(MS / 64, 2), 256, 0, stream>>>(
            kv_in, vW + wso, vb + bso, vbuf, MS, DD, DD, nullptr, 0, 0);
        ln_kernel<<<MR / 4, 256, 0, stream>>>(gridb, lnq_g + bso, lnq_b + bso, tmp1, MR);
        gemm_kernel<0, 0, 0><<<dim3(MR / 64, 2), 256, 0, stream>>>(
            tmp1, qW + wso, qb + bso, tmp2, MR, DD, DD, nullptr, 0, 0);
        attn_mfma_kernel<<<BB * NHEADS * (KGRID / 64), 256, 0, stream>>>(
            tmp2, kbuf, vbuf, sxy, dens, dist_raw + i, dens_raw + i, tmp1);
        gemm_kernel<0, 1, 0><<<dim3(MR / 64, 2), 256, 0, stream>>>(
            tmp1, oW + wso, ob + bso, gridb, MR, DD, DD, nullptr, 0, 0);
        ln_kernel<<<MR / 4, 256, 0, stream>>>(gridb, lnf_g + bso, lnf_b + bso, tmp1, MR);
        gemm_kernel<1, 0, 0><<<dim3(MR / 64, 4), 256, 0, stream>>>(
            tmp1, f1W + i * DD * 2 * DD, f1b + i * 2 * DD, tmp3, MR, DD, 2 * DD, nullptr, 0, 0);
        gemm_kernel<0, 1, 0><<<dim3(MR / 64, 2), 256, 0, stream>>>(
            tmp3, f2W + i * 2 * DD * DD, f2b + bso, gridb, MR, 2 * DD, DD, nullptr, 0, 0);
    }

    gemm_kernel<1, 0, 1><<<dim3(MR / 64, 2), 256, 0, stream>>>(
        gridb, tfp_W, tfp_b, tmp1, MR, DD, DD, task_id, DD * DD, DD);
    head_kernel<<<MR / 4, 256, 0, stream>>>(tmp1, head_W, head_b, (float*)d_out);
}

// Round 4
// 720.854 us; speedup vs baseline: 2.0699x; 1.2673x over previous
//
#include <hip/hip_runtime.h>
#include <math.h>

#define DD 256
#define NHEADS 8
#define HDIM 32
#define NLAYERS 2
#define GSZ 64
#define KGRID 4096      // GS*GS
#define TTASK 4
#define BB 4
#define NMEAS 511
#define SSRC 512        // N+1
#define HCITY 128
#define WCITY 128
#define ATT_SCALE 0.17677669529663687f   // 32^-0.5
#define INV2S2 78.125f                   // 1/(2*0.08^2)

typedef unsigned short u16;
typedef __attribute__((ext_vector_type(8))) short short8;
typedef __attribute__((ext_vector_type(4))) float f32x4;

__device__ __forceinline__ u16 f2bf(float f) {
    union { float f; unsigned int u; } x; x.f = f;
    return (u16)((x.u + 0x7fffu + ((x.u >> 16) & 1u)) >> 16);
}
__device__ __forceinline__ unsigned int pk2(float a, float b) {
    return (unsigned int)f2bf(a) | ((unsigned int)f2bf(b) << 16);
}
__device__ __forceinline__ float gelu_f(float x) {
    return 0.5f * x * (1.0f + erff(x * 0.7071067811865476f));
}

// ---------------------------------------------------------------------------
__global__ void task_vec_kernel(const float* __restrict__ task_emb,
                                const float* __restrict__ tpW,
                                const float* __restrict__ tpb,
                                const int* __restrict__ task_id,
                                float* __restrict__ tv) {
    int b = blockIdx.x, t = threadIdx.x;
    int id = task_id[b];
    float a = tpb[t];
    for (int e = 0; e < DD; e++) a = fmaf(task_emb[id * DD + e], tpW[e * DD + t], a);
    tv[b * DD + t] = a;
}

__global__ void grid_init_kernel(const float* __restrict__ grid_pos,
                                 const float* __restrict__ tv,
                                 float* __restrict__ g) {
    int f = blockIdx.x * 256 + threadIdx.x;
    int b = f >> 18;
    float4 gp = ((const float4*)grid_pos)[f & 262143];
    float4 tvv = ((const float4*)tv)[b * 64 + (f & 63)];
    float4 o; o.x = gp.x + tvv.x; o.y = gp.y + tvv.y; o.z = gp.z + tvv.z; o.w = gp.w + tvv.w;
    ((float4*)g)[f] = o;
}

// ---------------------------------------------------------------------------
__global__ __launch_bounds__(256) void src_build_kernel(
    const float* __restrict__ meas_xy, const float* __restrict__ meas_v,
    const float* __restrict__ bs_xy, const float* __restrict__ city,
    const float* __restrict__ meas_W, const float* __restrict__ meas_b,
    const float* __restrict__ pW1, const float* __restrict__ pb1,
    const float* __restrict__ pW2, const float* __restrict__ pb2,
    const float* __restrict__ bs_W, const float* __restrict__ bs_b,
    float* __restrict__ src, float* __restrict__ src_xy) {
    __shared__ float sp[81];
    __shared__ float sh[DD];
    int b = blockIdx.x / SSRC, s = blockIdx.x % SSRC, t = threadIdx.x;
    if (s < NMEAS) {
        float mx = meas_xy[(b * NMEAS + s) * 2];
        float my = meas_xy[(b * NMEAS + s) * 2 + 1];
        float mv = meas_v[b * NMEAS + s];
        int cx = (int)rintf(mx * 127.0f); cx = min(max(cx, 0), 127);
        int cy = (int)rintf(my * 127.0f); cy = min(max(cy, 0), 127);
        if (t < 81) {
            int rr = cy + t / 9 - 4, cc = cx + t % 9 - 4;
            sp[t] = (rr >= 0 && rr < HCITY && cc >= 0 && cc < WCITY)
                        ? city[(b * HCITY + rr) * WCITY + cc] : 0.0f;
        }
        __syncthreads();
        float a1 = pb1[t];
        #pragma unroll 9
        for (int e = 0; e < 81; e++) a1 = fmaf(sp[e], pW1[e * DD + t], a1);
        sh[t] = gelu_f(a1);
        __syncthreads();
        float a2 = pb2[t];
        for (int e = 0; e < DD; e++) a2 = fmaf(sh[e], pW2[e * DD + t], a2);
        float mt = mx * meas_W[t] + my * meas_W[DD + t] + mv * meas_W[2 * DD + t] + meas_b[t];
        src[((size_t)(b * SSRC + s)) * DD + t] = mt + a2;
        if (t == 0) { src_xy[(b * SSRC + s) * 2] = mx; src_xy[(b * SSRC + s) * 2 + 1] = my; }
    } else {
        float bx = bs_xy[b * 2], by = bs_xy[b * 2 + 1];
        src[((size_t)(b * SSRC + s)) * DD + t] = bx * bs_W[t] + by * bs_W[DD + t] + bs_b[t];
        if (t == 0) { src_xy[(b * SSRC + s) * 2] = bx; src_xy[(b * SSRC + s) * 2 + 1] = by; }
    }
}

// ---------------------------------------------------------------------------
__global__ void density_kernel(const float* __restrict__ meas_xy, float* __restrict__ dens) {
    int w = threadIdx.x >> 6, lane = threadIdx.x & 63;
    int idx = blockIdx.x * 4 + w;
    int b = idx >> 12, k = idx & 4095;
    float gx = ((k & 63) + 0.5f) * (1.0f / 64.0f);
    float gy = ((k >> 6) + 0.5f) * (1.0f / 64.0f);
    float s = 0.0f;
    for (int n = lane; n < NMEAS; n += 64) {
        float2 xy = ((const float2*)meas_xy)[b * NMEAS + n];
        float dx = gx - xy.x, dy = gy - xy.y;
        s += __expf(-(dx * dx + dy * dy) * INV2S2);
    }
    #pragma unroll
    for (int o = 1; o < 64; o <<= 1) s += __shfl_xor(s, o, 64);
    if (lane == 0) dens[idx] = s * (1.0f / 511.0f);
}

// ---------------------------------------------------------------------------
// LayerNorm: one wave per row of 256; bf16 output.
__global__ void ln_kernel(const float* __restrict__ X, const float* __restrict__ g,
                          const float* __restrict__ bvec, u16* __restrict__ Yb, int rows) {
    int w = threadIdx.x >> 6, lane = threadIdx.x & 63;
    int row = blockIdx.x * 4 + w;
    if (row >= rows) return;
    float4 x = ((const float4*)X)[(size_t)row * 64 + lane];
    float s = x.x + x.y + x.z + x.w;
    float q = x.x * x.x + x.y * x.y + x.z * x.z + x.w * x.w;
    #pragma unroll
    for (int o = 1; o < 64; o <<= 1) { s += __shfl_xor(s, o, 64); q += __shfl_xor(q, o, 64); }
    float m = s * (1.0f / 256.0f);
    float v = q * (1.0f / 256.0f) - m * m;
    float rs = rsqrtf(v + 1e-5f);
    float4 gg = ((const float4*)g)[lane], bb = ((const float4*)bvec)[lane];
    float4 y;
    y.x = (x.x - m) * rs * gg.x + bb.x;
    y.y = (x.y - m) * rs * gg.y + bb.y;
    y.z = (x.z - m) * rs * gg.z + bb.z;
    y.w = (x.w - m) * rs * gg.w + bb.w;
    uint2 o2;
    o2.x = pk2(y.x, y.y);
    o2.y = pk2(y.z, y.w);
    *(uint2*)&Yb[(size_t)row * 256 + lane * 4] = o2;
}

// ---------------------------------------------------------------------------
// Weight convert: W[z][Kd][Nd] fp32 -> Wt[z][Nd][Kd] bf16 (32x32 LDS tiles).
__global__ __launch_bounds__(256) void wconv_kernel(const float* __restrict__ W,
                                                    u16* __restrict__ Wt, int Kd, int Nd) {
    __shared__ float L[32][33];
    int z = blockIdx.z;
    size_t zoff = (size_t)z * Kd * Nd;
    int n0 = blockIdx.x * 32, k0 = blockIdx.y * 32;
    int tx = threadIdx.x, ty = threadIdx.y;
    #pragma unroll
    for (int yy = 0; yy < 4; yy++)
        L[tx][ty + 8 * yy] = W[zoff + (size_t)(k0 + ty + 8 * yy) * Nd + n0 + tx];
    __syncthreads();
    #pragma unroll
    for (int yy = 0; yy < 4; yy++)
        Wt[zoff + (size_t)(n0 + ty + 8 * yy) * Kd + k0 + tx] = f2bf(L[ty + 8 * yy][tx]);
}

// V transpose: V[b*512+s][256] bf16 -> Vt[(b*256+n)][512] bf16.
__global__ __launch_bounds__(256) void vtrans_kernel(const u16* __restrict__ V,
                                                     u16* __restrict__ Vt) {
    __shared__ u16 L[32][33];
    int b = blockIdx.z;
    int n0 = blockIdx.x * 32, s0 = blockIdx.y * 32;
    int tx = threadIdx.x, ty = threadIdx.y;
    #pragma unroll
    for (int yy = 0; yy < 4; yy++)
        L[tx][ty + 8 * yy] = V[(size_t)(b * SSRC + s0 + ty + 8 * yy) * DD + n0 + tx];
    __syncthreads();
    #pragma unroll
    for (int yy = 0; yy < 4; yy++)
        Vt[(size_t)(b * DD + n0 + ty + 8 * yy) * SSRC + s0 + tx] = L[ty + 8 * yy][tx];
}

// ---------------------------------------------------------------------------
// bf16 MFMA GEMM: C = [res +] act(A @ Wt^T + bias). A[M][Kd] bf16, Wt[N][Kd] bf16.
// Block: 64 m-rows x 128 n-cols, 4 waves (wave = 16 m-rows, 8 n-tiles). No LDS.
template <int ACT, int RES, int OBF, int OF32, int BATW>
__global__ __launch_bounds__(256) void gemm_mfma(
    const u16* __restrict__ A, const u16* __restrict__ Wt,
    const float* __restrict__ bias, float* __restrict__ C, u16* __restrict__ Cb,
    int M, int Kd, int Nfull, const int* __restrict__ task_id, int wstride, int bstride) {
    int t = threadIdx.x;
    int w = t >> 6, lane = t & 63, lq = lane & 15, g = lane >> 4;
    int mblk = blockIdx.x * 64;
    int n0 = blockIdx.y * 128;
    const u16* Wp = Wt;
    const float* bp = bias;
    if (BATW) {
        int id = task_id[mblk / KGRID];
        Wp += (size_t)id * wstride;
        bp += (size_t)id * bstride;
    }
    const u16* Ap = A + (size_t)(mblk + w * 16 + lq) * Kd + g * 8;
    const u16* Wr0 = Wp + (size_t)(n0 + lq) * Kd + g * 8;
    f32x4 acc[8];
    #pragma unroll
    for (int nt = 0; nt < 8; nt++) acc[nt] = {0.f, 0.f, 0.f, 0.f};
    for (int k = 0; k < Kd; k += 32) {
        short8 af = *(const short8*)(Ap + k);
        #pragma unroll
        for (int nt = 0; nt < 8; nt++) {
            short8 wf = *(const short8*)(Wr0 + (size_t)nt * 16 * Kd + k);
            acc[nt] = __builtin_amdgcn_mfma_f32_16x16x32_bf16(af, wf, acc[nt], 0, 0, 0);
        }
    }
    int mrow = mblk + w * 16 + 4 * g;
    #pragma unroll
    for (int nt = 0; nt < 8; nt++) {
        int col = n0 + nt * 16 + lq;
        float bv = bp[col];
        #pragma unroll
        for (int r = 0; r < 4; r++) {
            float o = acc[nt][r] + bv;
            if (ACT) o = gelu_f(o);
            size_t off = (size_t)(mrow + r) * Nfull + col;
            if (RES) o += C[off];
            if (OF32) C[off] = o;
            if (OBF) Cb[off] = f2bf(o);
        }
    }
}

// ---------------------------------------------------------------------------
// MFMA attention v2: no K/V staging (L2-resident bf16 K and per-head V^T).
// Block = (b, h, 64 q-rows); 4 waves x 16 q-rows. Swapped-operand layout:
// QK: D = mfma(K_rows, Q) -> D[s = 4g+r][q = lq]; softmax lane-local;
// P handoff via per-wave LDS; PV: O^T = mfma(V^T, P^T).
__global__ __launch_bounds__(256) void attn_mfma_kernel(
    const u16* __restrict__ Qb, const u16* __restrict__ Kb, const u16* __restrict__ Vt,
    const float* __restrict__ sxy_g, const float* __restrict__ dens,
    const float* __restrict__ dist_raw, const float* __restrict__ dens_raw,
    u16* __restrict__ O) {
    __shared__ float2 sxy[SSRC];
    __shared__ u16 sP[4][512];
    int blk = blockIdx.x;
    int kt = blk & 63, h = (blk >> 6) & 7, b = blk >> 9;
    int t = threadIdx.x;
    sxy[t]       = ((const float2*)sxy_g)[b * SSRC + t];
    sxy[t + 256] = ((const float2*)sxy_g)[b * SSRC + t + 256];
    __syncthreads();

    int lane = t & 63, w = t >> 6, lq = lane & 15, g = lane >> 4;
    int qrow = kt * 64 + w * 16 + lq;
    float gx = ((qrow & 63) + 0.5f) * (1.0f / 64.0f);
    float gy = ((qrow >> 6) + 0.5f) * (1.0f / 64.0f);
    const float LOG2E = 1.4426950408889634f;
    float gate = 1.0f + tanhf(dens_raw[0]) * dens[b * KGRID + qrow];
    float c1 = log1pf(__expf(dist_raw[0]));
    float gs = gate * ATT_SCALE * LOG2E;
    float gc = gate * c1 * LOG2E;

    short8 qf = *(const short8*)(Qb + (size_t)(b * KGRID + qrow) * DD + h * HDIM + g * 8);
    const u16* kbase = Kb + (size_t)b * SSRC * DD + h * HDIM + g * 8;
    const u16* vbase = Vt + ((size_t)(b * NHEADS + h) * HDIM + lq) * SSRC + g * 8;

    f32x4 acc0 = {0.f, 0.f, 0.f, 0.f}, acc1 = {0.f, 0.f, 0.f, 0.f};
    f32x4 zero = {0.f, 0.f, 0.f, 0.f};
    float lsum = 0.0f;
    u16* myP = sP[w];

    for (int s0 = 0; s0 < SSRC; s0 += 32) {
        #pragma unroll
        for (int tl = 0; tl < 2; tl++) {
            int sb = s0 + tl * 16;
            short8 kf = *(const short8*)(kbase + (size_t)(sb + lq) * DD);
            f32x4 c = __builtin_amdgcn_mfma_f32_16x16x32_bf16(kf, qf, zero, 0, 0, 0);
            float p[4];
            #pragma unroll
            for (int r = 0; r < 4; r++) {
                int s = sb + 4 * g + r;
                float2 xy = sxy[s];
                float dx = gx - xy.x, dy = gy - xy.y;
                float dist = sqrtf(dx * dx + dy * dy);
                p[r] = exp2f(gs * c[r] - gc * dist);
                lsum += p[r];
            }
            int idx = lq * 32 + tl * 16 + 4 * g;
            *(unsigned int*)&myP[idx]     = pk2(p[0], p[1]);
            *(unsigned int*)&myP[idx + 2] = pk2(p[2], p[3]);
        }
        short8 pf = *(const short8*)&myP[lq * 32 + g * 8];
        short8 v0 = *(const short8*)(vbase + s0);
        short8 v1 = *(const short8*)(vbase + 16 * SSRC + s0);
        acc0 = __builtin_amdgcn_mfma_f32_16x16x32_bf16(v0, pf, acc0, 0, 0, 0);
        acc1 = __builtin_amdgcn_mfma_f32_16x16x32_bf16(v1, pf, acc1, 0, 0, 0);
    }

    lsum += __shfl_xor(lsum, 16, 64);
    lsum += __shfl_xor(lsum, 32, 64);
    float inv = 1.0f / lsum;
    u16* op = O + (size_t)(b * KGRID + qrow) * DD + h * HDIM + 4 * g;
    uint2 o0, o1;
    o0.x = pk2(acc0[0] * inv, acc0[1] * inv);
    o0.y = pk2(acc0[2] * inv, acc0[3] * inv);
    o1.x = pk2(acc1[0] * inv, acc1[1] * inv);
    o1.y = pk2(acc1[2] * inv, acc1[3] * inv);
    *(uint2*)op = o0;
    *(uint2*)(op + 16) = o1;
}

// ---------------------------------------------------------------------------
__global__ void head_kernel(const float* __restrict__ tf, const float* __restrict__ hW,
                            const float* __restrict__ hb, float* __restrict__ out) {
    int w = threadIdx.x >> 6, lane = threadIdx.x & 63;
    int idx = blockIdx.x * 4 + w;
    float4 x = ((const float4*)tf)[(size_t)idx * 64 + lane];
    float4 ww = ((const float4*)hW)[lane];
    float s = x.x * ww.x + x.y * ww.y + x.z * ww.z + x.w * ww.w;
    #pragma unroll
    for (int o = 1; o < 64; o <<= 1) s += __shfl_xor(s, o, 64);
    if (lane == 0) out[idx] = s + hb[0];
}

// ---------------------------------------------------------------------------
extern "C" void kernel_launch(void* const* d_in, const int* in_sizes, int n_in,
                              void* d_out, int out_size, void* d_ws, size_t ws_size,
                              hipStream_t stream) {
    const float* meas_xy = (const float*)d_in[0];
    const float* meas_v  = (const float*)d_in[1];
    const float* bs_xy   = (const float*)d_in[2];
    const float* city    = (const float*)d_in[3];
    const float* meas_W  = (const float*)d_in[4];
    const float* meas_b  = (const float*)d_in[5];
    const float* pW1     = (const float*)d_in[6];
    const float* pb1     = (const float*)d_in[7];
    const float* pW2     = (const float*)d_in[8];
    const float* pb2     = (const float*)d_in[9];
    const float* bs_W    = (const float*)d_in[10];
    const float* bs_b    = (const float*)d_in[11];
    const float* task_emb= (const float*)d_in[12];
    const float* taskp_W = (const float*)d_in[13];
    const float* taskp_b = (const float*)d_in[14];
    const float* grid_pos= (const float*)d_in[15];
    const float* lnq_g   = (const float*)d_in[16];
    const float* lnq_b   = (const float*)d_in[17];
    const float* lnkv_g  = (const float*)d_in[18];
    const float* lnkv_b  = (const float*)d_in[19];
    const float* qW      = (const float*)d_in[20];
    const float* qb      = (const float*)d_in[21];
    const float* kW      = (const float*)d_in[22];
    const float* kb      = (const float*)d_in[23];
    const float* vW      = (const float*)d_in[24];
    const float* vb      = (const float*)d_in[25];
    const float* oW      = (const float*)d_in[26];
    const float* ob      = (const float*)d_in[27];
    const float* dist_raw= (const float*)d_in[28];
    const float* dens_raw= (const float*)d_in[29];
    const float* lnf_g   = (const float*)d_in[30];
    const float* lnf_b   = (const float*)d_in[31];
    const float* f1W     = (const float*)d_in[32];
    const float* f1b     = (const float*)d_in[33];
    const float* f2W     = (const float*)d_in[34];
    const float* f2b     = (const float*)d_in[35];
    const float* tfp_W   = (const float*)d_in[36];
    const float* tfp_b   = (const float*)d_in[37];
    const float* head_W  = (const float*)d_in[38];
    const float* head_b  = (const float*)d_in[39];
    const int*   task_id = (const int*)d_in[40];

    float* ws = (float*)d_ws;
    float* src   = ws;                       // 524288
    float* gridb = src + 524288;             // 4194304
    float* tmp1  = gridb + 4194304;          // 4194304 (task-gemm fp32 out)
    float* sxyb  = tmp1 + 4194304;           // 4096
    float* densb = sxyb + 4096;              // 16384
    float* tvec  = densb + 16384;            // 1024

    u16* wtq  = (u16*)(tvec + 1024);         // 131072 (2 layers)
    u16* wtk  = wtq  + 131072;
    u16* wtv  = wtk  + 131072;
    u16* wto  = wtv  + 131072;
    u16* wtf1 = wto  + 131072;               // 262144
    u16* wtf2 = wtf1 + 262144;               // 262144
    u16* wtt  = wtf2 + 262144;               // 262144
    u16* kvbf = wtt  + 262144;               // 524288
    u16* lnbf = kvbf + 524288;               // 4194304 (lnq/lnf/grid-final share)
    u16* qbf  = lnbf + 4194304;              // 4194304
    u16* kbf  = qbf  + 4194304;              // 524288
    u16* vbf  = kbf  + 524288;               // 524288
    u16* vtbf = vbf  + 524288;               // 524288
    u16* obf  = vtbf + 524288;               // 4194304
    u16* fhbf = obf  + 4194304;              // 8388608

    const dim3 B32x8(32, 8);

    task_vec_kernel<<<BB, 256, 0, stream>>>(task_emb, taskp_W, taskp_b, task_id, tvec);
    grid_init_kernel<<<4096, 256, 0, stream>>>(grid_pos, tvec, gridb);
    src_build_kernel<<<BB * SSRC, 256, 0, stream>>>(meas_xy, meas_v, bs_xy, city,
                                                    meas_W, meas_b, pW1, pb1, pW2, pb2,
                                                    bs_W, bs_b, src, sxyb);
    density_kernel<<<4096, 256, 0, stream>>>(meas_xy, densb);

    wconv_kernel<<<dim3(8, 8, 2), B32x8, 0, stream>>>(qW, wtq, 256, 256);
    wconv_kernel<<<dim3(8, 8, 2), B32x8, 0, stream>>>(kW, wtk, 256, 256);
    wconv_kernel<<<dim3(8, 8, 2), B32x8, 0, stream>>>(vW, wtv, 256, 256);
    wconv_kernel<<<dim3(8, 8, 2), B32x8, 0, stream>>>(oW, wto, 256, 256);
    wconv_kernel<<<dim3(16, 8, 2), B32x8, 0, stream>>>(f1W, wtf1, 256, 512);
    wconv_kernel<<<dim3(8, 16, 2), B32x8, 0, stream>>>(f2W, wtf2, 512, 256);
    wconv_kernel<<<dim3(8, 8, 4), B32x8, 0, stream>>>(tfp_W, wtt, 256, 256);

    for (int i = 0; i < NLAYERS; i++) {
        const int w16 = i * 65536, bso = i * DD;
        ln_kernel<<<512, 256, 0, stream>>>(src, lnkv_g + bso, lnkv_b + bso, kvbf, 2048);
        gemm_mfma<0, 0, 1, 0, 0><<<dim3(32, 2), 256, 0, stream>>>(
            kvbf, wtk + w16, kb + bso, tmp1, kbf, 2048, 256, 256, nullptr, 0, 0);
        gemm_mfma<0, 0, 1, 0, 0><<<dim3(32, 2), 256, 0, stream>>>(
            kvbf, wtv + w16, vb + bso, tmp1, vbf, 2048, 256, 256, nullptr, 0, 0);
        vtrans_kernel<<<dim3(8, 16, 4), B32x8, 0, stream>>>(vbf, vtbf);
        ln_kernel<<<4096, 256, 0, stream>>>(gridb, lnq_g + bso, lnq_b + bso, lnbf, 16384);
        gemm_mfma<0, 0, 1, 0, 0><<<dim3(256, 2), 256, 0, stream>>>(
            lnbf, wtq + w16, qb + bso, tmp1, qbf, 16384, 256, 256, nullptr, 0, 0);
        attn_mfma_kernel<<<2048, 256, 0, stream>>>(
            qbf, kbf, vtbf, sxyb, densb, dist_raw + i, dens_raw + i, obf);
        gemm_mfma<0, 1, 0, 1, 0><<<dim3(256, 2), 256, 0, stream>>>(
            obf, wto + w16, ob + bso, gridb, obf, 16384, 256, 256, nullptr, 0, 0);
        ln_kernel<<<4096, 256, 0, stream>>>(gridb, lnf_g + bso, lnf_b + bso, lnbf, 16384);
        gemm_mfma<1, 0, 1, 0, 0><<<dim3(256, 4), 256, 0, stream>>>(
            lnbf, wtf1 + i * 131072, f1b + i * 512, tmp1, fhbf, 16384, 256, 512, nullptr, 0, 0);
        gemm_mfma<0, 1, 1, 1, 0><<<dim3(256, 2), 256, 0, stream>>>(
            fhbf, wtf2 + i * 131072, f2b + bso, gridb, lnbf, 16384, 512, 256, nullptr, 0, 0);
    }

    gemm_mfma<1, 0, 0, 1, 1><<<dim3(256, 2), 256, 0, stream>>>(
        lnbf, wtt, tfp_b, tmp1, obf, 16384, 256, 256, task_id, 65536, 256);
    head_kernel<<<4096, 256, 0, stream>>>(tmp1, head_W, head_b, (float*)d_out);
}